// Round 1
// baseline (262.275 us; speedup 1.0000x reference)
//
#include <hip/hip_runtime.h>
#include <hip/hip_bf16.h>

// Problem constants (from reference setup_inputs)
#define N_TRAIN 4096
#define N_UNL   32768
#define C_DIM   1000
#define G_GRP   512
#define K_MEM   64

typedef short  short8 __attribute__((ext_vector_type(8)));   // 8 bf16 in 4 VGPRs
typedef float  f32x4  __attribute__((ext_vector_type(4)));   // MFMA accumulator

__device__ __forceinline__ unsigned short f2bf(float f) {
    unsigned int u = __float_as_uint(f);
    u += 0x7fffu + ((u >> 16) & 1u);          // round-to-nearest-even
    return (unsigned short)(u >> 16);
}
__device__ __forceinline__ float bf2f(unsigned short h) {
    return __uint_as_float(((unsigned int)h) << 16);
}

// ---------------------------------------------------------------------------
// Cross-entropy: one wave per row, 16 strided elements per lane.
// ---------------------------------------------------------------------------
__global__ __launch_bounds__(256) void ce_kernel(const float* __restrict__ logits,
                                                 const int*   __restrict__ targets,
                                                 float* __restrict__ out) {
    const int wave = threadIdx.x >> 6;
    const int lane = threadIdx.x & 63;
    const int row  = blockIdx.x * 4 + wave;            // grid = 1024 blocks
    const float* rp = logits + (long)row * C_DIM;

    float x[16];
#pragma unroll
    for (int i = 0; i < 16; ++i) {
        int c = lane + i * 64;
        x[i] = (c < C_DIM) ? rp[c] : -1e30f;
    }
    float m = x[0];
#pragma unroll
    for (int i = 1; i < 16; ++i) m = fmaxf(m, x[i]);
#pragma unroll
    for (int off = 32; off > 0; off >>= 1) m = fmaxf(m, __shfl_xor(m, off, 64));

    float s = 0.f;
#pragma unroll
    for (int i = 0; i < 16; ++i) s += __expf(x[i] - m);
#pragma unroll
    for (int off = 32; off > 0; off >>= 1) s += __shfl_xor(s, off, 64);

    if (lane == 0) {
        int t = targets[row];
        float lp = rp[t] - m - __logf(s);
        atomicAdd(out, -lp * (1.0f / (float)N_TRAIN));
    }
}

// ---------------------------------------------------------------------------
// Fused group kernel: one block per group (512 blocks, 256 threads = 4 waves).
//  - stage members [64 x 128] chunk as bf16 in LDS (row pitch 136 = +8 pad)
//  - 64x64 gram via mfma_f32_16x16x32_bf16 (wave w owns tile-row w)
//  - sq[i] = gram diagonal; robust = sum_{i<j} sqrt(max(sq_i+sq_j-2*gram,0))
//  - align dots c·m_k on VALU from the same LDS tile, sq_c on staging threads
// ---------------------------------------------------------------------------
#define CHUNK   128
#define PITCH   136     // bf16 elements per LDS row: 272 B (16B-aligned, 2-way banks)

__global__ __launch_bounds__(256) void group_kernel(const float* __restrict__ train_logits,
                                                    const float* __restrict__ unl,
                                                    const int*   __restrict__ centroid_ids,
                                                    const int*   __restrict__ member_ids,
                                                    float* __restrict__ out) {
    __shared__ unsigned short m_sh[K_MEM * PITCH];   // 17408 B
    __shared__ float c_sh[CHUNK];
    __shared__ float sq_sh[K_MEM];
    __shared__ float dotp_sh[256];
    __shared__ float red_sh[256];
    __shared__ float sqc_sh;

    const int g    = blockIdx.x;
    const int tid  = threadIdx.x;
    const int wave = tid >> 6;
    const int lane = tid & 63;
    const int quad = lane >> 4;
    const int c16  = lane & 15;

    // staging assignment: 4 threads per member row, 8 float4 each per chunk
    const int  mrow   = tid >> 2;                       // 0..63
    const int  f4base = tid & 3;                        // 0..3
    const long mbase  = (long)member_ids[g * K_MEM + mrow] * C_DIM;
    const long cbase  = (long)centroid_ids[g] * C_DIM;

    // align-dot assignment: thread handles member k = tid&63, dims [dseg, dseg+32)
    const int kmem = tid & 63;
    const int dseg = (tid >> 6) * 32;

    f32x4 acc[4];
#pragma unroll
    for (int t = 0; t < 4; ++t) acc[t] = (f32x4){0.f, 0.f, 0.f, 0.f};
    float dotp = 0.f;     // partial of c · m_k over this thread's dim segment
    float sqcp = 0.f;     // partial of ||c||^2 (threads 0..31 only)

    for (int ch = 0; ch < 8; ++ch) {
        const int col0 = ch * CHUNK;
        // ---- stage members -> bf16 LDS ----
#pragma unroll
        for (int i = 0; i < 8; ++i) {
            int f4  = f4base + i * 4;                   // 0..31
            int col = col0 + f4 * 4;
            float4 v;
            if (col < C_DIM) v = *(const float4*)(unl + mbase + col);
            else             v = make_float4(0.f, 0.f, 0.f, 0.f);
            ushort4 h;
            h.x = f2bf(v.x); h.y = f2bf(v.y); h.z = f2bf(v.z); h.w = f2bf(v.w);
            *(ushort4*)&m_sh[mrow * PITCH + f4 * 4] = h;
        }
        // ---- stage centroid (fp32) + sq_c partial ----
        if (tid < 32) {
            int col = col0 + tid * 4;
            float4 v;
            if (col < C_DIM) v = *(const float4*)(train_logits + cbase + col);
            else             v = make_float4(0.f, 0.f, 0.f, 0.f);
            *(float4*)&c_sh[tid * 4] = v;
            sqcp += v.x * v.x + v.y * v.y + v.z * v.z + v.w * v.w;
        }
        __syncthreads();

        // ---- align dot partial (VALU), b128 LDS reads ----
#pragma unroll
        for (int s = 0; s < 4; ++s) {
            short8 mv = *(const short8*)&m_sh[kmem * PITCH + dseg + s * 8];
#pragma unroll
            for (int j = 0; j < 8; ++j) {
                dotp = fmaf(c_sh[dseg + s * 8 + j], bf2f((unsigned short)mv[j]), dotp);
            }
        }

        // ---- MFMA gram: wave w computes tiles (w, 0..3) ----
#pragma unroll
        for (int ks = 0; ks < 4; ++ks) {
            int kb = ks * 32 + quad * 8;
            short8 a = *(const short8*)&m_sh[(wave * 16 + c16) * PITCH + kb];
#pragma unroll
            for (int t = 0; t < 4; ++t) {
                short8 b = *(const short8*)&m_sh[(t * 16 + c16) * PITCH + kb];
                acc[t] = __builtin_amdgcn_mfma_f32_16x16x32_bf16(a, b, acc[t], 0, 0, 0);
            }
        }
        __syncthreads();   // protect LDS before next chunk's staging
    }

    // ---- extract gram diagonal -> sq_sh ----
    // C/D layout: row = quad*4 + reg, col = lane&15 (within tile)
#pragma unroll
    for (int r = 0; r < 4; ++r) {
        int il = quad * 4 + r;
        if (c16 == il) sq_sh[wave * 16 + il] = acc[wave][r];
    }
    dotp_sh[tid] = dotp;
    red_sh[tid] = (tid < 32) ? sqcp : 0.f;
    __syncthreads();
    // reduce sq_c
    for (int s = 128; s > 0; s >>= 1) {
        if (tid < s) red_sh[tid] += red_sh[tid + s];
        __syncthreads();
    }
    if (tid == 0) sqc_sh = red_sh[0];
    __syncthreads();

    float local = 0.f;
    // ---- align: threads 0..63, member k = tid ----
    if (tid < 64) {
        float dot = dotp_sh[tid] + dotp_sh[tid + 64] + dotp_sh[tid + 128] + dotp_sh[tid + 192];
        float d2 = sqc_sh + sq_sh[tid] - 2.f * dot;
        if (d2 > 0.f) local += sqrtf(d2) * (1.0f / (float)N_UNL);   // LAMBDA_1 = 1.0
    }
    // ---- robust: upper triangle of 64x64 from accumulators ----
#pragma unroll
    for (int t = 0; t < 4; ++t) {
#pragma unroll
        for (int r = 0; r < 4; ++r) {
            int i = wave * 16 + quad * 4 + r;
            int j = t * 16 + c16;
            if (j > i) {
                float d2 = sq_sh[i] + sq_sh[j] - 2.f * acc[t][r];
                if (d2 > 0.f) local += sqrtf(d2) * (0.5f / ((float)K_MEM * (float)N_UNL)); // LAMBDA_2=0.5
            }
        }
    }

    red_sh[tid] = local;
    __syncthreads();
    for (int s = 128; s > 0; s >>= 1) {
        if (tid < s) red_sh[tid] += red_sh[tid + s];
        __syncthreads();
    }
    if (tid == 0) atomicAdd(out, red_sh[0]);
}

// ---------------------------------------------------------------------------
extern "C" void kernel_launch(void* const* d_in, const int* in_sizes, int n_in,
                              void* d_out, int out_size, void* d_ws, size_t ws_size,
                              hipStream_t stream) {
    (void)in_sizes; (void)n_in; (void)d_ws; (void)ws_size; (void)out_size;
    const float* train_logits = (const float*)d_in[0];
    const int*   train_targets = (const int*)d_in[1];
    const float* unl           = (const float*)d_in[2];
    const int*   centroid_ids  = (const int*)d_in[3];
    const int*   member_ids    = (const int*)d_in[4];
    float* out = (float*)d_out;

    hipMemsetAsync(out, 0, sizeof(float), stream);
    ce_kernel<<<N_TRAIN / 4, 256, 0, stream>>>(train_logits, train_targets, out);
    group_kernel<<<G_GRP, 256, 0, stream>>>(train_logits, unl, centroid_ids, member_ids, out);
}

// Round 2
// 240.943 us; speedup vs baseline: 1.0885x; 1.0885x over previous
//
#include <hip/hip_runtime.h>
#include <hip/hip_bf16.h>

// Problem constants (from reference setup_inputs)
#define N_TRAIN 4096
#define N_UNL   32768
#define C_DIM   1000
#define G_GRP   512
#define K_MEM   64
#define CPAD    1024            // padded bf16 row pitch (cols 1000..1023 zero)

typedef short          short8 __attribute__((ext_vector_type(8)));   // 8 bf16 (4 VGPRs)
typedef float          f32x4  __attribute__((ext_vector_type(4)));   // MFMA accumulator
typedef unsigned short us4    __attribute__((ext_vector_type(4)));   // 8 B store

__device__ __forceinline__ unsigned short f2bf(float f) {
    unsigned int u = __float_as_uint(f);
    u += 0x7fffu + ((u >> 16) & 1u);          // round-to-nearest-even
    return (unsigned short)(u >> 16);
}

// async global->LDS, 16 B per lane; LDS dest = wave-uniform base + lane*16
__device__ __forceinline__ void async16(void* ldsdst, const void* gsrc) {
    __builtin_amdgcn_global_load_lds(
        (const __attribute__((address_space(1))) unsigned int*)gsrc,
        (__attribute__((address_space(3))) unsigned int*)ldsdst,
        16, 0, 0);
}

// ---------------------------------------------------------------------------
// bf16 precompute: unlabeled rows 0..32767 -> bf_unl[row][1024],
//                  gathered centroids    -> bf_cent[g][1024], pad cols zeroed.
// Slot = (row, t): t<250 converts float4 -> 4 bf16; t in [250,256) writes zeros.
// ---------------------------------------------------------------------------
__global__ __launch_bounds__(256) void conv_kernel(const float* __restrict__ unl,
                                                   const float* __restrict__ train,
                                                   const int*   __restrict__ cids,
                                                   unsigned short* __restrict__ bf_unl,
                                                   unsigned short* __restrict__ bf_cent) {
    const int total = (N_UNL + G_GRP) * 256;
    for (int s = blockIdx.x * 256 + threadIdx.x; s < total; s += gridDim.x * 256) {
        const int row = s >> 8;
        const int t   = s & 255;
        const float* src;
        unsigned short* dst;
        if (row < N_UNL) {
            src = unl + (long)row * C_DIM;
            dst = bf_unl + (long)row * CPAD;
        } else {
            const int g = row - N_UNL;
            src = train + (long)cids[g] * C_DIM;
            dst = bf_cent + (long)g * CPAD;
        }
        us4 h = (us4){0, 0, 0, 0};
        if (t < 250) {
            float4 v = *(const float4*)(src + t * 4);
            h[0] = f2bf(v.x); h[1] = f2bf(v.y); h[2] = f2bf(v.z); h[3] = f2bf(v.w);
        }
        *(us4*)(dst + t * 4) = h;
    }
}

// ---------------------------------------------------------------------------
// Cross-entropy: one wave per row; block partial -> part[bid]. NO atomics.
// ---------------------------------------------------------------------------
__global__ __launch_bounds__(256) void ce_kernel(const float* __restrict__ logits,
                                                 const int*   __restrict__ targets,
                                                 float* __restrict__ part) {
    const int wave = threadIdx.x >> 6;
    const int lane = threadIdx.x & 63;
    const int row  = blockIdx.x * 4 + wave;
    const float* rp = logits + (long)row * C_DIM;
    __shared__ float pr[4];

    float x[16];
#pragma unroll
    for (int i = 0; i < 16; ++i) {
        int c = lane + i * 64;
        x[i] = (c < C_DIM) ? rp[c] : -1e30f;
    }
    float m = x[0];
#pragma unroll
    for (int i = 1; i < 16; ++i) m = fmaxf(m, x[i]);
#pragma unroll
    for (int off = 32; off > 0; off >>= 1) m = fmaxf(m, __shfl_xor(m, off, 64));

    float s = 0.f;
#pragma unroll
    for (int i = 0; i < 16; ++i) s += __expf(x[i] - m);
#pragma unroll
    for (int off = 32; off > 0; off >>= 1) s += __shfl_xor(s, off, 64);

    if (lane == 0) {
        int t = targets[row];
        pr[wave] = -(rp[t] - m - __logf(s));
    }
    __syncthreads();
    if (threadIdx.x == 0)
        part[blockIdx.x] = (pr[0] + pr[1] + pr[2] + pr[3]) * (1.0f / (float)N_TRAIN);
}

// ---------------------------------------------------------------------------
// Group kernel v2: one block per group, 4 waves.
// LDS tile: 80 bf16 rows x 256 cols per chunk, 4 chunks (K padded to 1024).
//   rows 0..63  = members, row 64 = centroid, rows 65..79 = zeros.
//   row-pair layout: pair p at p*1040 B (2x512 B + 16 B pad -> even bank spread)
// Staged via global_load_lds (1 instr = 2 rows). Gram (incl. centroid row) via
// mfma_f32_16x16x32_bf16. align + robust from accumulators. Partial -> part.
// ---------------------------------------------------------------------------
#define PAIR_PITCH 1040
#define NPAIRS     40
#define LDSZ       (NPAIRS * PAIR_PITCH)   // 41600 B

__global__ __launch_bounds__(256) void group_kernel(const unsigned short* __restrict__ bf_unl,
                                                    const unsigned short* __restrict__ bf_cent,
                                                    const int* __restrict__ member_ids,
                                                    float* __restrict__ part) {
    __shared__ __align__(16) unsigned char lds[LDSZ];
    __shared__ float sq_sh[K_MEM];
    __shared__ float red_sh[256];
    __shared__ float sqc_sh;

    const int g    = blockIdx.x;
    const int tid  = threadIdx.x;
    const int w    = tid >> 6;
    const int lane = tid & 63;
    const int quad = lane >> 4;
    const int c16  = lane & 15;

    // lane r holds member id of row r (per wave)
    const int mid = member_ids[g * K_MEM + lane];

    // zero rows 65..79 (+ pads): bytes [32*1040+512, 41600)
    {
        const int base = 32 * PAIR_PITCH + 512;          // 33792
        for (int off = tid * 16; off < LDSZ - base; off += 256 * 16)
            *(float4*)(lds + base + off) = make_float4(0.f, 0.f, 0.f, 0.f);
    }

    f32x4 acc[4], accC, accD;
#pragma unroll
    for (int t = 0; t < 4; ++t) acc[t] = (f32x4){0.f, 0.f, 0.f, 0.f};
    accC = (f32x4){0.f, 0.f, 0.f, 0.f};
    accD = (f32x4){0.f, 0.f, 0.f, 0.f};

    // per-lane LDS read offsets (row r -> (r>>1)*1040 + (r&1)*512)
    const unsigned offB0 = (unsigned)(c16 >> 1) * PAIR_PITCH + (unsigned)(c16 & 1) * 512;
    const unsigned offA  = offB0 + (unsigned)w * (8 * PAIR_PITCH);       // rows w*16+c16
    const unsigned offC  = offB0 + 32u * PAIR_PITCH;                     // rows 64+c16

    for (int ch = 0; ch < 4; ++ch) {
        const int colB = ch * 256;                        // element offset into padded row
        // ---- stage member pairs: wave w stages pairs w*8 .. w*8+7 ----
#pragma unroll
        for (int i = 0; i < 8; ++i) {
            const int p = w * 8 + i;
            const int r = 2 * p + (lane >> 5);
            const int rid = __shfl(mid, r, 64);
            const unsigned short* src = bf_unl + (long)rid * CPAD + colB + (lane & 31) * 8;
            async16(lds + p * PAIR_PITCH, src);
        }
        // ---- stage centroid row (pair 32, lanes 0..31 only), wave 1 ----
        if (w == 1 && lane < 32) {
            const unsigned short* src = bf_cent + (long)g * CPAD + colB + (lane & 31) * 8;
            async16(lds + 32 * PAIR_PITCH, src);
        }
        __syncthreads();   // drains vmcnt -> LDS tile ready

        // ---- MFMA: tiles (w,0..3), (4,w), and (4,4) on wave 0 ----
#pragma unroll
        for (int s = 0; s < 8; ++s) {
            const unsigned kb = (unsigned)(s * 32 + quad * 8) * 2;
            short8 b0 = *(const short8*)(lds + offB0 + 0 * 8 * PAIR_PITCH + kb);
            short8 b1 = *(const short8*)(lds + offB0 + 1 * 8 * PAIR_PITCH + kb);
            short8 b2 = *(const short8*)(lds + offB0 + 2 * 8 * PAIR_PITCH + kb);
            short8 b3 = *(const short8*)(lds + offB0 + 3 * 8 * PAIR_PITCH + kb);
            short8 aM = *(const short8*)(lds + offA + kb);
            short8 aC = *(const short8*)(lds + offC + kb);
            acc[0] = __builtin_amdgcn_mfma_f32_16x16x32_bf16(aM, b0, acc[0], 0, 0, 0);
            acc[1] = __builtin_amdgcn_mfma_f32_16x16x32_bf16(aM, b1, acc[1], 0, 0, 0);
            acc[2] = __builtin_amdgcn_mfma_f32_16x16x32_bf16(aM, b2, acc[2], 0, 0, 0);
            acc[3] = __builtin_amdgcn_mfma_f32_16x16x32_bf16(aM, b3, acc[3], 0, 0, 0);
            accC   = __builtin_amdgcn_mfma_f32_16x16x32_bf16(aC, aM, accC, 0, 0, 0);
            if (w == 0)
                accD = __builtin_amdgcn_mfma_f32_16x16x32_bf16(aC, aC, accD, 0, 0, 0);
        }
        __syncthreads();   // all waves done reading before next chunk's staging
    }

    // ---- gram diagonal -> sq_sh (tile (w,w): i = w*16+quad*4+r, j = w*16+c16) ----
#pragma unroll
    for (int t = 0; t < 4; ++t) {
        if (t == w) {
#pragma unroll
            for (int r = 0; r < 4; ++r)
                if (c16 == quad * 4 + r) sq_sh[w * 16 + c16] = acc[t][r];
        }
    }
    if (tid == 0) sqc_sh = accD[0];   // gram[64][64] = ||c||^2 (wave0, lane0, reg0)
    __syncthreads();

    float local = 0.f;
    // ---- align: tile (4,w) row 64 -> quad==0, reg 0; col j = w*16+c16 ----
    if (quad == 0) {
        const int j = w * 16 + c16;
        const float d2 = sqc_sh + sq_sh[j] - 2.f * accC[0];
        if (d2 > 0.f) local += sqrtf(d2) * (1.0f / (float)N_UNL);       // LAMBDA_1 = 1
    }
    // ---- robust: upper triangle of member gram ----
#pragma unroll
    for (int t = 0; t < 4; ++t) {
#pragma unroll
        for (int r = 0; r < 4; ++r) {
            const int i = w * 16 + quad * 4 + r;
            const int j = t * 16 + c16;
            if (j > i) {
                const float d2 = sq_sh[i] + sq_sh[j] - 2.f * acc[t][r];
                if (d2 > 0.f)
                    local += sqrtf(d2) * (0.5f / ((float)K_MEM * (float)N_UNL)); // LAMBDA_2=0.5
            }
        }
    }

    red_sh[tid] = local;
    __syncthreads();
#pragma unroll
    for (int s = 128; s > 0; s >>= 1) {
        if (tid < s) red_sh[tid] += red_sh[tid + s];
        __syncthreads();
    }
    if (tid == 0) part[N_TRAIN / 4 + g] = red_sh[0];
}

// ---------------------------------------------------------------------------
// Final reduce: 1024 CE partials + 512 group partials -> out[0].
// ---------------------------------------------------------------------------
__global__ __launch_bounds__(256) void final_kernel(const float* __restrict__ part,
                                                    float* __restrict__ out, int out_size) {
    __shared__ float red[256];
    float s = 0.f;
    for (int i = threadIdx.x; i < N_TRAIN / 4 + G_GRP; i += 256) s += part[i];
    red[threadIdx.x] = s;
    __syncthreads();
#pragma unroll
    for (int st = 128; st > 0; st >>= 1) {
        if (threadIdx.x < st) red[threadIdx.x] += red[threadIdx.x + st];
        __syncthreads();
    }
    if (threadIdx.x == 0) out[0] = red[0];
    for (int i = 1 + threadIdx.x; i < out_size; i += 256) out[i] = 0.f;  // poison guard
}

// ---------------------------------------------------------------------------
extern "C" void kernel_launch(void* const* d_in, const int* in_sizes, int n_in,
                              void* d_out, int out_size, void* d_ws, size_t ws_size,
                              hipStream_t stream) {
    (void)in_sizes; (void)n_in; (void)ws_size;
    const float* train_logits  = (const float*)d_in[0];
    const int*   train_targets = (const int*)d_in[1];
    const float* unl           = (const float*)d_in[2];
    const int*   centroid_ids  = (const int*)d_in[3];
    const int*   member_ids    = (const int*)d_in[4];
    float* out = (float*)d_out;

    char* ws = (char*)d_ws;
    unsigned short* bf_unl  = (unsigned short*)ws;                          // 67,108,864 B
    unsigned short* bf_cent = (unsigned short*)(ws + (size_t)N_UNL * CPAD * 2);   // 1,048,576 B
    float* part = (float*)(ws + (size_t)(N_UNL + G_GRP) * CPAD * 2);        // 1536 floats

    conv_kernel<<<4096, 256, 0, stream>>>(unl, train_logits, centroid_ids, bf_unl, bf_cent);
    ce_kernel<<<N_TRAIN / 4, 256, 0, stream>>>(train_logits, train_targets, part);
    group_kernel<<<G_GRP, 256, 0, stream>>>(bf_unl, bf_cent, member_ids, part);
    final_kernel<<<1, 256, 0, stream>>>(part, out, out_size);
}

// Round 3
// 217.145 us; speedup vs baseline: 1.2078x; 1.1096x over previous
//
#include <hip/hip_runtime.h>

// Problem constants (from reference setup_inputs)
#define N_TRAIN 4096
#define N_UNL   32768
#define C_DIM   1000
#define G_GRP   512
#define K_MEM   64

#define CE_BLOCKS (N_TRAIN / 16)          // 256 blocks, 16 rows each
#define NPART     (G_GRP + CE_BLOCKS)     // 768 partials

#define PITCH_B 528                       // LDS row pitch in BYTES (264 bf16)
#define ROWS    80                        // 64 members + centroid + 15 zero rows

typedef short        short8 __attribute__((ext_vector_type(8)));   // 8 bf16 (4 VGPRs)
typedef float        f32x4  __attribute__((ext_vector_type(4)));   // MFMA accumulator
typedef unsigned int u32x4  __attribute__((ext_vector_type(4)));   // 16 B store

// pack two f32 -> two bf16 (round-half-up via +0x8000; inputs are ~N(0,1), no overflow risk)
__device__ __forceinline__ unsigned int pack_bf(float a, float b) {
    unsigned int ua = __float_as_uint(a) + 0x8000u;
    unsigned int ub = __float_as_uint(b) + 0x8000u;
    return (ua >> 16) | (ub & 0xffff0000u);
}

// ---------------------------------------------------------------------------
// Fused kernel. Blocks 0..511: group path (gather fp32 -> bf16 LDS -> MFMA gram
// -> align+robust partial). Blocks 512..767: CE path (16 rows each).
// ---------------------------------------------------------------------------
__global__ __launch_bounds__(256) void fused_kernel(const float* __restrict__ train,
                                                    const int*   __restrict__ targets,
                                                    const float* __restrict__ unl,
                                                    const int*   __restrict__ cids,
                                                    const int*   __restrict__ mids,
                                                    float* __restrict__ part) {
    __shared__ __align__(16) unsigned short bf[ROWS * (PITCH_B / 2)];  // 42240 B
    __shared__ int   ids_sh[K_MEM];
    __shared__ float sq_sh[K_MEM];
    __shared__ float red_sh[256];
    __shared__ float sqc_sh;

    const int tid  = threadIdx.x;
    const int w    = tid >> 6;
    const int lane = tid & 63;

    if (blockIdx.x >= G_GRP) {
        // ------------------------- CE path -------------------------
        const int blk = (int)blockIdx.x - G_GRP;
        float ce = 0.f;
        for (int r4 = 0; r4 < 4; ++r4) {
            const int row = blk * 16 + w * 4 + r4;
            const float* rp = train + (long)row * C_DIM;
            float x[16];
#pragma unroll
            for (int i = 0; i < 16; ++i) {
                int c = lane + i * 64;
                x[i] = (c < C_DIM) ? rp[c] : -1e30f;
            }
            float m = x[0];
#pragma unroll
            for (int i = 1; i < 16; ++i) m = fmaxf(m, x[i]);
#pragma unroll
            for (int off = 32; off > 0; off >>= 1) m = fmaxf(m, __shfl_xor(m, off, 64));
            float s = 0.f;
#pragma unroll
            for (int i = 0; i < 16; ++i) s += __expf(x[i] - m);
#pragma unroll
            for (int off = 32; off > 0; off >>= 1) s += __shfl_xor(s, off, 64);
            if (lane == 0) {
                int t = targets[row];
                ce += -(rp[t] - m - __logf(s));
            }
        }
        if (lane == 0) red_sh[w] = ce;
        __syncthreads();
        if (tid == 0)
            part[G_GRP + blk] = (red_sh[0] + red_sh[1] + red_sh[2] + red_sh[3]) *
                                (1.0f / (float)N_TRAIN);
        return;
    }

    // ------------------------- group path -------------------------
    const int g    = blockIdx.x;
    const int quad = lane >> 4;
    const int c16  = lane & 15;

    // zero rows 65..79 (their MFMA contributions must vanish): 15*528 = 7920 B
    for (int idx = tid; idx < 495; idx += 256)
        *(u32x4*)((char*)bf + 65 * PITCH_B + idx * 16) = (u32x4){0, 0, 0, 0};
    if (tid < K_MEM) ids_sh[tid] = mids[g * K_MEM + tid];
    __syncthreads();

    // staging map: wave w lanes 0..31 -> row 2w+8i, lanes 32..63 -> row 2w+1+8i
    const int rgrp = tid >> 5;          // 0..7
    const int l32  = tid & 31;
    const int colf = l32 * 8;           // float col within 256-col chunk
    const int cid  = cids[g];

    const float* srcb[8];
#pragma unroll
    for (int i = 0; i < 8; ++i)
        srcb[i] = unl + (long)ids_sh[rgrp + 8 * i] * C_DIM + colf;
    const float* csrc = train + (long)cid * C_DIM + colf;

    f32x4 acc[4], accC, accD;
#pragma unroll
    for (int t = 0; t < 4; ++t) acc[t] = (f32x4){0.f, 0.f, 0.f, 0.f};
    accC = (f32x4){0.f, 0.f, 0.f, 0.f};
    accD = (f32x4){0.f, 0.f, 0.f, 0.f};

    const float4 z4 = make_float4(0.f, 0.f, 0.f, 0.f);

    for (int ch = 0; ch < 4; ++ch) {
        const int col = ch * 256 + colf;
        const bool v0 = (col < C_DIM);          // float4 [col, col+3] fully valid
        const bool v1 = (col + 4 < C_DIM);      // float4 [col+4, col+7]
        // ---- stage member rows: 8 rows/iter, fp32 gather -> bf16 ds_write_b128 ----
#pragma unroll
        for (int i = 0; i < 8; ++i) {
            float4 a = v0 ? *(const float4*)(srcb[i] + ch * 256) : z4;
            float4 b = v1 ? *(const float4*)(srcb[i] + ch * 256 + 4) : z4;
            u32x4 h = {pack_bf(a.x, a.y), pack_bf(a.z, a.w),
                       pack_bf(b.x, b.y), pack_bf(b.z, b.w)};
            *(u32x4*)((char*)bf + (rgrp + 8 * i) * PITCH_B + colf * 2) = h;
        }
        // ---- stage centroid row 64 (threads 0..31) ----
        if (tid < 32) {
            float4 a = v0 ? *(const float4*)(csrc + ch * 256) : z4;
            float4 b = v1 ? *(const float4*)(csrc + ch * 256 + 4) : z4;
            u32x4 h = {pack_bf(a.x, a.y), pack_bf(a.z, a.w),
                       pack_bf(b.x, b.y), pack_bf(b.z, b.w)};
            *(u32x4*)((char*)bf + 64 * PITCH_B + colf * 2) = h;
        }
        __syncthreads();

        // ---- MFMA: tiles (w,0..3), centroid x (w), and ||c||^2 on wave 0 ----
#pragma unroll
        for (int s = 0; s < 8; ++s) {
            const int kbb = s * 64 + quad * 16;     // byte offset within row segment
            const char* base = (const char*)bf;
            short8 b0 = *(const short8*)(base + (0 * 16 + c16) * PITCH_B + kbb);
            short8 b1 = *(const short8*)(base + (1 * 16 + c16) * PITCH_B + kbb);
            short8 b2 = *(const short8*)(base + (2 * 16 + c16) * PITCH_B + kbb);
            short8 b3 = *(const short8*)(base + (3 * 16 + c16) * PITCH_B + kbb);
            short8 aM = *(const short8*)(base + (w * 16 + c16) * PITCH_B + kbb);
            short8 aC = *(const short8*)(base + (64 + c16) * PITCH_B + kbb);
            acc[0] = __builtin_amdgcn_mfma_f32_16x16x32_bf16(aM, b0, acc[0], 0, 0, 0);
            acc[1] = __builtin_amdgcn_mfma_f32_16x16x32_bf16(aM, b1, acc[1], 0, 0, 0);
            acc[2] = __builtin_amdgcn_mfma_f32_16x16x32_bf16(aM, b2, acc[2], 0, 0, 0);
            acc[3] = __builtin_amdgcn_mfma_f32_16x16x32_bf16(aM, b3, acc[3], 0, 0, 0);
            accC   = __builtin_amdgcn_mfma_f32_16x16x32_bf16(aC, aM, accC, 0, 0, 0);
            if (w == 0)
                accD = __builtin_amdgcn_mfma_f32_16x16x32_bf16(aC, aC, accD, 0, 0, 0);
        }
        __syncthreads();
    }

    // ---- gram diagonal -> sq_sh (tile (w,w): i = w*16+quad*4+r, j = w*16+c16) ----
#pragma unroll
    for (int t = 0; t < 4; ++t) {
        if (t == w) {
#pragma unroll
            for (int r = 0; r < 4; ++r)
                if (c16 == quad * 4 + r) sq_sh[w * 16 + c16] = acc[t][r];
        }
    }
    if (tid == 0) sqc_sh = accD[0];        // ||c||^2
    __syncthreads();

    float local = 0.f;
    // align: centroid-tile row 64 -> quad==0, reg 0; col j = w*16+c16
    if (quad == 0) {
        const int j = w * 16 + c16;
        const float d2 = sqc_sh + sq_sh[j] - 2.f * accC[0];
        if (d2 > 0.f) local += sqrtf(d2) * (1.0f / (float)N_UNL);        // LAMBDA_1 = 1
    }
    // robust: upper triangle of member gram
#pragma unroll
    for (int t = 0; t < 4; ++t) {
#pragma unroll
        for (int r = 0; r < 4; ++r) {
            const int i = w * 16 + quad * 4 + r;
            const int j = t * 16 + c16;
            if (j > i) {
                const float d2 = sq_sh[i] + sq_sh[j] - 2.f * acc[t][r];
                if (d2 > 0.f)
                    local += sqrtf(d2) * (0.5f / ((float)K_MEM * (float)N_UNL)); // L2=0.5
            }
        }
    }

    red_sh[tid] = local;
    __syncthreads();
#pragma unroll
    for (int s = 128; s > 0; s >>= 1) {
        if (tid < s) red_sh[tid] += red_sh[tid + s];
        __syncthreads();
    }
    if (tid == 0) part[g] = red_sh[0];
}

// ---------------------------------------------------------------------------
// Final reduce: 768 partials -> out[0].
// ---------------------------------------------------------------------------
__global__ __launch_bounds__(256) void final_kernel(const float* __restrict__ part,
                                                    float* __restrict__ out, int out_size) {
    __shared__ float red[256];
    float s = 0.f;
    for (int i = threadIdx.x; i < NPART; i += 256) s += part[i];
    red[threadIdx.x] = s;
    __syncthreads();
#pragma unroll
    for (int st = 128; st > 0; st >>= 1) {
        if (threadIdx.x < st) red[threadIdx.x] += red[threadIdx.x + st];
        __syncthreads();
    }
    if (threadIdx.x == 0) out[0] = red[0];
    for (int i = 1 + threadIdx.x; i < out_size; i += 256) out[i] = 0.f;  // poison guard
}

// ---------------------------------------------------------------------------
extern "C" void kernel_launch(void* const* d_in, const int* in_sizes, int n_in,
                              void* d_out, int out_size, void* d_ws, size_t ws_size,
                              hipStream_t stream) {
    (void)in_sizes; (void)n_in; (void)ws_size;
    const float* train_logits  = (const float*)d_in[0];
    const int*   train_targets = (const int*)d_in[1];
    const float* unl           = (const float*)d_in[2];
    const int*   centroid_ids  = (const int*)d_in[3];
    const int*   member_ids    = (const int*)d_in[4];
    float* out  = (float*)d_out;
    float* part = (float*)d_ws;            // 768 floats of scratch

    fused_kernel<<<NPART, 256, 0, stream>>>(train_logits, train_targets, unl,
                                            centroid_ids, member_ids, part);
    final_kernel<<<1, 256, 0, stream>>>(part, out, out_size);
}

// Round 4
// 210.418 us; speedup vs baseline: 1.2464x; 1.0320x over previous
//
#include <hip/hip_runtime.h>

// Problem constants (from reference setup_inputs)
#define N_TRAIN 4096
#define N_UNL   32768
#define C_DIM   1000
#define G_GRP   512
#define K_MEM   64

#define CE_BLOCKS (N_TRAIN / 16)          // 256 blocks, 16 rows each
#define NBLK      (G_GRP + CE_BLOCKS)     // 768 blocks total

#define CHUNKS  8
#define CCOLS   128                       // fp32 columns per chunk
#define PITCH_B 272                       // LDS row pitch BYTES (128 bf16 + 16 pad; 4-bank stride)
#define ROWS    80                        // 64 members + centroid + 15 zero rows

typedef short        short8 __attribute__((ext_vector_type(8)));   // 8 bf16 (4 VGPRs)
typedef float        f32x4  __attribute__((ext_vector_type(4)));   // MFMA accumulator
typedef unsigned int u32x2  __attribute__((ext_vector_type(2)));   // 8 B store
typedef unsigned int u32x4  __attribute__((ext_vector_type(4)));   // 16 B store

// pack two f32 -> two bf16 (round-half-up via +0x8000; inputs ~N(0,1), no overflow risk)
__device__ __forceinline__ unsigned int pack_bf(float a, float b) {
    unsigned int ua = __float_as_uint(a) + 0x8000u;
    unsigned int ub = __float_as_uint(b) + 0x8000u;
    return (ua >> 16) | (ub & 0xffff0000u);
}

// ---------------------------------------------------------------------------
// Fused kernel. Blocks 0..511: group path (register-prefetch pipelined gather
// -> bf16 LDS -> MFMA gram -> align+robust partial -> atomicAdd).
// Blocks 512..767: CE path (16 rows each -> atomicAdd).
// ---------------------------------------------------------------------------
__global__ __launch_bounds__(256) void fused_kernel(const float* __restrict__ train,
                                                    const int*   __restrict__ targets,
                                                    const float* __restrict__ unl,
                                                    const int*   __restrict__ cids,
                                                    const int*   __restrict__ mids,
                                                    float* __restrict__ out) {
    __shared__ __align__(16) unsigned short bf[ROWS * (PITCH_B / 2)];  // 21760 B
    __shared__ int   ids_sh[K_MEM];
    __shared__ float sq_sh[K_MEM];
    __shared__ float red_sh[256];
    __shared__ float sqc_sh;

    const int tid  = threadIdx.x;
    const int w    = tid >> 6;
    const int lane = tid & 63;

    if (blockIdx.x >= G_GRP) {
        // ------------------------- CE path -------------------------
        const int blk = (int)blockIdx.x - G_GRP;
        float ce = 0.f;
        for (int r4 = 0; r4 < 4; ++r4) {
            const int row = blk * 16 + w * 4 + r4;
            const float* rp = train + (long)row * C_DIM;
            float x[16];
#pragma unroll
            for (int i = 0; i < 16; ++i) {
                int c = lane + i * 64;
                x[i] = (c < C_DIM) ? rp[c] : -1e30f;
            }
            float m = x[0];
#pragma unroll
            for (int i = 1; i < 16; ++i) m = fmaxf(m, x[i]);
#pragma unroll
            for (int off = 32; off > 0; off >>= 1) m = fmaxf(m, __shfl_xor(m, off, 64));
            float s = 0.f;
#pragma unroll
            for (int i = 0; i < 16; ++i) s += __expf(x[i] - m);
#pragma unroll
            for (int off = 32; off > 0; off >>= 1) s += __shfl_xor(s, off, 64);
            if (lane == 0) {
                int t = targets[row];
                ce += -(rp[t] - m - __logf(s));
            }
        }
        if (lane == 0) red_sh[w] = ce;
        __syncthreads();
        if (tid == 0)
            atomicAdd(out, (red_sh[0] + red_sh[1] + red_sh[2] + red_sh[3]) *
                           (1.0f / (float)N_TRAIN));
        return;
    }

    // ------------------------- group path -------------------------
    const int g    = blockIdx.x;
    const int quad = lane >> 4;
    const int c16  = lane & 15;

    // zero rows 65..79 (their MFMA contributions must vanish): 15*272 = 4080 B
    if (tid < 255)
        *(u32x4*)((char*)bf + 65 * PITCH_B + tid * 16) = (u32x4){0, 0, 0, 0};
    if (tid < K_MEM) ids_sh[tid] = mids[g * K_MEM + tid];
    __syncthreads();

    // staging map: thread (rgrp,l32) owns rows rgrp+8i, fp32 cols [l32*4, l32*4+4)
    const int rgrp = tid >> 5;          // 0..7
    const int l32  = tid & 31;
    const int cid  = cids[g];

    const float* srcb[8];
#pragma unroll
    for (int i = 0; i < 8; ++i)
        srcb[i] = unl + (long)ids_sh[rgrp + 8 * i] * C_DIM + l32 * 4;
    const float* csrc = train + (long)cid * C_DIM + l32 * 4;    // used by tid<32 only

    f32x4 acc[4], accC, accD;
#pragma unroll
    for (int t = 0; t < 4; ++t) acc[t] = (f32x4){0.f, 0.f, 0.f, 0.f};
    accC = (f32x4){0.f, 0.f, 0.f, 0.f};
    accD = (f32x4){0.f, 0.f, 0.f, 0.f};

    const float4 z4 = make_float4(0.f, 0.f, 0.f, 0.f);

    float4 mreg[8];
    float4 creg;

    // prefetch chunk 0
    {
        const bool v = (l32 * 4 < C_DIM);   // always true for ch=0
#pragma unroll
        for (int i = 0; i < 8; ++i) mreg[i] = v ? *(const float4*)(srcb[i]) : z4;
        if (tid < 32) creg = *(const float4*)(csrc);
    }

    for (int ch = 0; ch < CHUNKS; ++ch) {
        __syncthreads();   // previous chunk's readers done (iter 0: zero-init done)

        // ---- commit prefetched regs -> bf16 LDS (ds_write_b64) ----
#pragma unroll
        for (int i = 0; i < 8; ++i) {
            u32x2 h = {pack_bf(mreg[i].x, mreg[i].y), pack_bf(mreg[i].z, mreg[i].w)};
            *(u32x2*)((char*)bf + (rgrp + 8 * i) * PITCH_B + l32 * 8) = h;
        }
        if (tid < 32) {
            u32x2 h = {pack_bf(creg.x, creg.y), pack_bf(creg.z, creg.w)};
            *(u32x2*)((char*)bf + 64 * PITCH_B + tid * 8) = h;
        }
        __syncthreads();

        // ---- issue next chunk's global loads (overlap with MFMA below) ----
        if (ch + 1 < CHUNKS) {
            const int col = (ch + 1) * CCOLS + l32 * 4;
            const bool v = (col < C_DIM);
            const long off = (long)(ch + 1) * CCOLS;
#pragma unroll
            for (int i = 0; i < 8; ++i) mreg[i] = v ? *(const float4*)(srcb[i] + off) : z4;
            if (tid < 32) creg = v ? *(const float4*)(csrc + off) : z4;
        }

        // ---- MFMA: tiles (w,0..3), centroid x (w), and ||c||^2 on wave 0 ----
#pragma unroll
        for (int s = 0; s < 4; ++s) {
            const int kbb = s * 64 + quad * 16;     // byte offset within 256 B row chunk
            const char* base = (const char*)bf;
            short8 b0 = *(const short8*)(base + (0 * 16 + c16) * PITCH_B + kbb);
            short8 b1 = *(const short8*)(base + (1 * 16 + c16) * PITCH_B + kbb);
            short8 b2 = *(const short8*)(base + (2 * 16 + c16) * PITCH_B + kbb);
            short8 b3 = *(const short8*)(base + (3 * 16 + c16) * PITCH_B + kbb);
            short8 aM = *(const short8*)(base + (w * 16 + c16) * PITCH_B + kbb);
            short8 aC = *(const short8*)(base + (64 + c16) * PITCH_B + kbb);
            acc[0] = __builtin_amdgcn_mfma_f32_16x16x32_bf16(aM, b0, acc[0], 0, 0, 0);
            acc[1] = __builtin_amdgcn_mfma_f32_16x16x32_bf16(aM, b1, acc[1], 0, 0, 0);
            acc[2] = __builtin_amdgcn_mfma_f32_16x16x32_bf16(aM, b2, acc[2], 0, 0, 0);
            acc[3] = __builtin_amdgcn_mfma_f32_16x16x32_bf16(aM, b3, acc[3], 0, 0, 0);
            accC   = __builtin_amdgcn_mfma_f32_16x16x32_bf16(aC, aM, accC, 0, 0, 0);
            if (w == 0)
                accD = __builtin_amdgcn_mfma_f32_16x16x32_bf16(aC, aC, accD, 0, 0, 0);
        }
    }

    // ---- gram diagonal -> sq_sh (tile (w,w): i = w*16+quad*4+r, j = w*16+c16) ----
#pragma unroll
    for (int t = 0; t < 4; ++t) {
        if (t == w) {
#pragma unroll
            for (int r = 0; r < 4; ++r)
                if (c16 == quad * 4 + r) sq_sh[w * 16 + c16] = acc[t][r];
        }
    }
    if (tid == 0) sqc_sh = accD[0];        // ||c||^2
    __syncthreads();

    float local = 0.f;
    // align: centroid-tile row 64 -> quad==0, reg 0; col j = w*16+c16
    if (quad == 0) {
        const int j = w * 16 + c16;
        const float d2 = sqc_sh + sq_sh[j] - 2.f * accC[0];
        if (d2 > 0.f) local += sqrtf(d2) * (1.0f / (float)N_UNL);        // LAMBDA_1 = 1
    }
    // robust: upper triangle of member gram
#pragma unroll
    for (int t = 0; t < 4; ++t) {
#pragma unroll
        for (int r = 0; r < 4; ++r) {
            const int i = w * 16 + quad * 4 + r;
            const int j = t * 16 + c16;
            if (j > i) {
                const float d2 = sq_sh[i] + sq_sh[j] - 2.f * acc[t][r];
                if (d2 > 0.f)
                    local += sqrtf(d2) * (0.5f / ((float)K_MEM * (float)N_UNL)); // L2=0.5
            }
        }
    }

    red_sh[tid] = local;
    __syncthreads();
#pragma unroll
    for (int s = 128; s > 0; s >>= 1) {
        if (tid < s) red_sh[tid] += red_sh[tid + s];
        __syncthreads();
    }
    if (tid == 0) atomicAdd(out, red_sh[0]);
}

// ---------------------------------------------------------------------------
extern "C" void kernel_launch(void* const* d_in, const int* in_sizes, int n_in,
                              void* d_out, int out_size, void* d_ws, size_t ws_size,
                              hipStream_t stream) {
    (void)in_sizes; (void)n_in; (void)d_ws; (void)ws_size;
    const float* train_logits  = (const float*)d_in[0];
    const int*   train_targets = (const int*)d_in[1];
    const float* unl           = (const float*)d_in[2];
    const int*   centroid_ids  = (const int*)d_in[3];
    const int*   member_ids    = (const int*)d_in[4];
    float* out = (float*)d_out;

    hipMemsetAsync(out, 0, (size_t)out_size * sizeof(float), stream);
    fused_kernel<<<NBLK, 256, 0, stream>>>(train_logits, train_targets, unl,
                                           centroid_ids, member_ids, out);
}